// Round 5
// baseline (2247.296 us; speedup 1.0000x reference)
//
#include <hip/hip_runtime.h>
#include <hip/hip_bf16.h>

#define B_ 512
#define T_ 512

typedef __bf16 bf16x8 __attribute__((ext_vector_type(8)));
typedef float  f32x4  __attribute__((ext_vector_type(4)));
using u16 = unsigned short;

__device__ __forceinline__ float fast_rcp(float x) { return __builtin_amdgcn_rcpf(x); }
__device__ __forceinline__ float sigf(float x)     { return fast_rcp(1.0f + __expf(-x)); }
__device__ __forceinline__ float tanhfast(float x) { return 1.0f - 2.0f * fast_rcp(__expf(2.0f * x) + 1.0f); }

// fp32 -> bf16 RNE
__device__ __forceinline__ u16 f2bf(float f) {
    unsigned u = __float_as_uint(f);
    u += 0x7FFFu + ((u >> 16) & 1u);
    return (u16)(u >> 16);
}

// Light barrier: orders LDS only; global stores/loads stay in flight
// (avoids the m97-style vmcnt(0) barrier drain).
__device__ __forceinline__ void lbar() {
    asm volatile("s_waitcnt lgkmcnt(0)\n\ts_barrier" ::: "memory");
}

// DPP quad-perm move (VALU pipe, keeps shuffles off the LDS pipe).
// 0xB1 = quad_perm[1,0,3,2] (lane^1), 0x4E = quad_perm[2,3,0,1] (lane^2).
template<int CTRL>
__device__ __forceinline__ float dppq(float v) {
    int r = __builtin_amdgcn_update_dpp(0, __float_as_int(v), CTRL, 0xF, 0xF, true);
    return __int_as_float(r);
}

__device__ __forceinline__ void spin_flag(const unsigned* f, unsigned target) {
    while (__hip_atomic_load(f, __ATOMIC_RELAXED, __HIP_MEMORY_SCOPE_AGENT) < target) {
        __builtin_amdgcn_s_sleep(1);
    }
    asm volatile("" ::: "memory");
}

// One LSTM layer as a device function (1/3 of the fused grid).
// 16 batch rows per block; weights as MFMA B-fragments in VGPRs; gate cols
// reordered n=4u+g -> DPP 4x4 transpose keeps c-state in-lane.
// Handshake (per-pb flags, chunked 4 steps/flag):
//   producer: release-add flag[chunk] at t%4==1 for chunk (t-5)/4 (stores >=2
//             iters old -> vmcnt drain nearly free); tail chunk after loop.
//   consumer: polls flag[t/4+1] at t%4==0 (3-step lookahead hides LLC latency)
// h1/h2 move as agent-scope bf16 atomics (LLC-coherent across XCDs).
template<int D, int H, int WACT, int TPW, bool IN_F32, bool OUT_F32, int IN_NW>
__device__ __forceinline__ void lstm_dev(
    const void* __restrict__ xin,
    const float* __restrict__ Wih, const float* __restrict__ Whh,
    const float* __restrict__ bih, const float* __restrict__ bhh,
    void* __restrict__ hout,          // u16 [B,T,H] (producer) or f32 (last)
    float* __restrict__ hn,           // [B,H], last layer only
    unsigned* __restrict__ inflag,    // [NCH] this pb's input flags
    unsigned* __restrict__ outflag,   // [NCH] this pb's output flags
    int pb, u16* smem)
{
    constexpr int K    = D + H;
    constexpr int KF   = (K + 31) / 32;
    constexpr int SSTR = KF * 32 + 8;      // bf16 stride; +8 -> cheap bank spread
    constexpr int NT   = 512;
    constexpr int XW   = 16 * D / 2;       // dwords of x staged per step
    constexpr int NCH  = T_ / 4;

    const int tid  = threadIdx.x;
    const int lane = tid & 63;
    const int wv   = tid >> 6;
    const int q    = lane >> 4;
    const int cc   = lane & 15;
    const int b0   = pb * 16;
    const bool act = (wv < WACT);

    u16* xc0 = smem;
    u16* xc1 = smem + 16 * SSTR;

    // ---- B-fragments (weights), bias, c-state ----
    bf16x8 WB[TPW][KF];
    float  bias[TPW][4];
    float  cst[TPW];
    if (act) {
#pragma unroll
        for (int tp = 0; tp < TPW; ++tp) {
            const int nglob = (wv * TPW + tp) * 16 + cc;
            const int u = nglob >> 2, g = nglob & 3;
            const int row = g * H + u;
#pragma unroll
            for (int kf = 0; kf < KF; ++kf) {
                bf16x8 w;
#pragma unroll
                for (int jj = 0; jj < 8; ++jj) {
                    const int k = kf * 32 + q * 8 + jj;
                    float v = 0.0f;
                    if (k < D)      v = Wih[row * D + k];
                    else if (k < K) v = Whh[row * H + (k - D)];
                    w[jj] = (__bf16)v;
                }
                WB[tp][kf] = w;
            }
            const int uu = (wv * TPW + tp) * 4 + (cc >> 2);
#pragma unroll
            for (int g2 = 0; g2 < 4; ++g2)
                bias[tp][g2] = bih[g2 * H + uu] + bhh[g2 * H + uu];
            cst[tp] = 0.0f;
        }
    }

    // ---- init LDS (zeros incl. K padding), stage x_0 ----
    for (int i = tid; i < 2 * 16 * SSTR; i += NT) smem[i] = 0;
    lbar();
    const int xr = tid / (D / 2);
    const int xp = tid % (D / 2);
    if constexpr (!IN_F32) {
        if (tid < XW) spin_flag(&inflag[0], IN_NW);   // chunk 0 covers t=0..3
    }
    if (tid < XW) {
        unsigned pk;
        const size_t gi = ((size_t)(b0 + xr) * T_ + 0) * (D / 2) + xp;
        if constexpr (IN_F32) {
            const float2 f = ((const float2*)xin)[gi];
            pk = (unsigned)f2bf(f.x) | ((unsigned)f2bf(f.y) << 16);
        } else {
            pk = __hip_atomic_load(&((const unsigned*)xin)[gi],
                                   __ATOMIC_RELAXED, __HIP_MEMORY_SCOPE_AGENT);
        }
        *(unsigned*)&xc0[xr * SSTR + 2 * xp] = pk;
    }
    lbar();

    const f32x4 zed = {0.0f, 0.0f, 0.0f, 0.0f};
    const int  rr = 4 * q + (lane & 3);
    const bool bA = lane & 1, bB = lane & 2;

    for (int t = 0; t < T_; ++t) {
        u16* cur = (t & 1) ? xc1 : xc0;
        u16* nxt = (t & 1) ? xc0 : xc1;

        // ---- A-fragments for step t ----
        bf16x8 A[KF];
        if (act) {
#pragma unroll
            for (int kf = 0; kf < KF; ++kf)
                A[kf] = *(const bf16x8*)&cur[cc * SSTR + kf * 32 + q * 8];
        }

        // ---- producer signal (chunked; before the prefetch load so the
        //      release's vmcnt drain excludes it) ----
        if constexpr (!OUT_F32) {
            if (t >= 5 && (t & 3) == 1 && act && lane == 0)
                __hip_atomic_fetch_add(&outflag[(t - 5) >> 2], 1u,
                                       __ATOMIC_RELEASE, __HIP_MEMORY_SCOPE_AGENT);
        }

        // ---- prefetch x_{t+1} (chunk flag was verified >=3 steps earlier) ----
        unsigned pk = 0;
        const bool hasx = (t + 1 < T_) && (tid < XW);
        if (hasx) {
            const size_t gi = ((size_t)(b0 + xr) * T_ + (t + 1)) * (D / 2) + xp;
            if constexpr (IN_F32) {
                const float2 f = ((const float2*)xin)[gi];
                pk = (unsigned)f2bf(f.x) | ((unsigned)f2bf(f.y) << 16);
            } else {
                pk = __hip_atomic_load(&((const unsigned*)xin)[gi],
                                       __ATOMIC_RELAXED, __HIP_MEMORY_SCOPE_AGENT);
            }
        }

        // ---- MFMA ----
        f32x4 acc[TPW];
        if (act) {
#pragma unroll
            for (int tp = 0; tp < TPW; ++tp) acc[tp] = zed;
#pragma unroll
            for (int kf = 0; kf < KF; ++kf)
#pragma unroll
                for (int tp = 0; tp < TPW; ++tp)
                    acc[tp] = __builtin_amdgcn_mfma_f32_16x16x32_bf16(A[kf], WB[tp][kf], acc[tp], 0, 0, 0);
        }

        // ---- consumer poll, 3-step lookahead (placed after MFMA issue so the
        //      LLC read overlaps gate math) ----
        if constexpr (!IN_F32) {
            if ((t & 3) == 0 && ((t >> 2) + 1) < NCH && tid < XW)
                spin_flag(&inflag[(t >> 2) + 1], IN_NW);
        }

        // ---- DPP 4x4 transpose + gates + state update ----
        if (act) {
#pragma unroll
            for (int tp = 0; tp < TPW; ++tp) {
                float v0 = acc[tp][0], v1 = acc[tp][1], v2 = acc[tp][2], v3 = acc[tp][3];
                float s;
                s = dppq<0xB1>(bA ? v0 : v1); if (bA) v0 = s; else v1 = s;
                s = dppq<0xB1>(bA ? v2 : v3); if (bA) v2 = s; else v3 = s;
                s = dppq<0x4E>(bB ? v0 : v2); if (bB) v0 = s; else v2 = s;
                s = dppq<0x4E>(bB ? v1 : v3); if (bB) v1 = s; else v3 = s;

                const float gi = sigf(v0 + bias[tp][0]);
                const float gf = sigf(v1 + bias[tp][1]);
                const float gg = tanhfast(v2 + bias[tp][2]);
                const float go = sigf(v3 + bias[tp][3]);
                const float c  = gf * cst[tp] + gi * gg;
                cst[tp] = c;
                const float h  = go * tanhfast(c);

                const int u = (wv * TPW + tp) * 4 + (cc >> 2);
                nxt[rr * SSTR + D + u] = f2bf(h);
                const size_t oi = ((size_t)(b0 + rr) * T_ + t) * H + u;
                if constexpr (OUT_F32) {
                    ((float*)hout)[oi] = h;
                    if (t == T_ - 1) hn[(b0 + rr) * H + u] = h;
                } else {
                    __hip_atomic_store(&((u16*)hout)[oi], f2bf(h),
                                       __ATOMIC_RELAXED, __HIP_MEMORY_SCOPE_AGENT);
                }
            }
        }

        // ---- stage x_{t+1} ----
        if (hasx) *(unsigned*)&nxt[xr * SSTR + 2 * xp] = pk;

        lbar();
    }

    // ---- tail signal: last chunk (steps T-4..T-1) ----
    if constexpr (!OUT_F32) {
        if (act && lane == 0)
            __hip_atomic_fetch_add(&outflag[NCH - 1], 1u,
                                   __ATOMIC_RELEASE, __HIP_MEMORY_SCOPE_AGENT);
    }
}

// Fused 3-layer pipeline: blocks [0,32)=L1, [32,64)=L2, [64,96)=L3.
// 96 blocks << 256 CUs -> all co-resident; layers overlap via per-pb flags.
__global__ __launch_bounds__(512)
void lstm_fused(const float* __restrict__ z,
                const float* __restrict__ Wih1, const float* __restrict__ Whh1,
                const float* __restrict__ bih1, const float* __restrict__ bhh1,
                const float* __restrict__ Wih2, const float* __restrict__ Whh2,
                const float* __restrict__ bih2, const float* __restrict__ bhh2,
                const float* __restrict__ Wih3, const float* __restrict__ Whh3,
                const float* __restrict__ bih3, const float* __restrict__ bhh3,
                float* __restrict__ out, float* __restrict__ hn,
                u16* __restrict__ h1, u16* __restrict__ h2,
                unsigned* __restrict__ f1, unsigned* __restrict__ f2)
{
    extern __shared__ u16 smem[];
    constexpr int NCH = T_ / 4;
    const int bx = blockIdx.x;
    const int layer = bx >> 5;
    const int pb = bx & 31;
    if (layer == 0) {
        // D=64 H=32, 8 waves x 1 tile; producer of h1 (8 signals/chunk)
        lstm_dev<64, 32, 8, 1, true, false, 0>(z, Wih1, Whh1, bih1, bhh1,
                                               h1, nullptr, nullptr, f1 + pb * NCH, pb, smem);
    } else if (layer == 1) {
        // D=32 H=48, 6 active waves x 2 tiles; consumes h1 (wait 8), produces h2
        lstm_dev<32, 48, 6, 2, false, false, 8>(h1, Wih2, Whh2, bih2, bhh2,
                                                h2, nullptr, f1 + pb * NCH, f2 + pb * NCH, pb, smem);
    } else {
        // D=48 H=128, 8 waves x 4 tiles; consumes h2 (wait 6), fp32 out+hn
        lstm_dev<48, 128, 8, 4, false, true, 6>(h2, Wih3, Whh3, bih3, bhh3,
                                                out, hn, f2 + pb * NCH, nullptr, pb, smem);
    }
}

extern "C" void kernel_launch(void* const* d_in, const int* in_sizes, int n_in,
                              void* d_out, int out_size, void* d_ws, size_t ws_size,
                              hipStream_t stream)
{
    (void)in_sizes; (void)n_in; (void)out_size; (void)ws_size;
    const float* z    = (const float*)d_in[0];
    const float* Wih1 = (const float*)d_in[1];
    const float* Whh1 = (const float*)d_in[2];
    const float* bih1 = (const float*)d_in[3];
    const float* bhh1 = (const float*)d_in[4];
    const float* Wih2 = (const float*)d_in[5];
    const float* Whh2 = (const float*)d_in[6];
    const float* bih2 = (const float*)d_in[7];
    const float* bhh2 = (const float*)d_in[8];
    const float* Wih3 = (const float*)d_in[9];
    const float* Whh3 = (const float*)d_in[10];
    const float* bih3 = (const float*)d_in[11];
    const float* bhh3 = (const float*)d_in[12];

    constexpr int NCH = T_ / 4;
    // ws layout: [f1 32*NCH u32 | f2 32*NCH u32 | h1 bf16 B*T*32 | h2 bf16 B*T*48]
    unsigned* f1 = (unsigned*)d_ws;
    unsigned* f2 = f1 + 32 * NCH;
    u16* h1 = (u16*)(f2 + 32 * NCH);
    u16* h2 = h1 + (size_t)B_ * T_ * 32;

    float* out = (float*)d_out;                  // [B,T,128]
    float* hn  = out + (size_t)B_ * T_ * 128;    // [1,B,128]

    // zero the flags (ws is poisoned 0xAA before every call)
    hipMemsetAsync(d_ws, 0, 2 * 32 * NCH * sizeof(unsigned), stream);

    hipLaunchKernelGGL(lstm_fused, dim3(96), dim3(512), 12800, stream,
                       z, Wih1, Whh1, bih1, bhh1,
                       Wih2, Whh2, bih2, bhh2,
                       Wih3, Whh3, bih3, bhh3,
                       out, hn, h1, h2, f1, f2);
}

// Round 6
// 1531.076 us; speedup vs baseline: 1.4678x; 1.4678x over previous
//
#include <hip/hip_runtime.h>
#include <hip/hip_bf16.h>

#define B_ 512
#define T_ 512

typedef __bf16 bf16x8 __attribute__((ext_vector_type(8)));
typedef float  f32x4  __attribute__((ext_vector_type(4)));
using u16 = unsigned short;

__device__ __forceinline__ float fast_rcp(float x) { return __builtin_amdgcn_rcpf(x); }
__device__ __forceinline__ float sigf(float x)     { return fast_rcp(1.0f + __expf(-x)); }
__device__ __forceinline__ float tanhfast(float x) { return 1.0f - 2.0f * fast_rcp(__expf(2.0f * x) + 1.0f); }

// fp32 -> bf16 RNE
__device__ __forceinline__ u16 f2bf(float f) {
    unsigned u = __float_as_uint(f);
    u += 0x7FFFu + ((u >> 16) & 1u);
    return (u16)(u >> 16);
}

// Light barrier: orders LDS only; global stores stay in flight across steps
// (removes the vmcnt(0) barrier drain that dominated r3: 3343 cy/step vs
// ~900 cy of work). Field-verified correct in r5.
__device__ __forceinline__ void lbar() {
    asm volatile("s_waitcnt lgkmcnt(0)\n\ts_barrier" ::: "memory");
}

// DPP quad-perm move (VALU pipe; keeps the 4x4 transpose off the LDS pipe).
// 0xB1 = quad_perm[1,0,3,2] (lane^1), 0x4E = quad_perm[2,3,0,1] (lane^2).
// Field-verified correct in r5.
template<int CTRL>
__device__ __forceinline__ float dppq(float v) {
    int r = __builtin_amdgcn_update_dpp(0, __float_as_int(v), CTRL, 0xF, 0xF, true);
    return __int_as_float(r);
}

// Persistent MFMA LSTM layer (one dispatch per layer; kernel boundary = the
// cheap cross-XCD coherence point — r5 proved agent-scope flag pipelining
// costs more than it saves on gfx950).
// 32 blocks x 16 batch rows; weights as MFMA B-fragments in VGPRs, gate cols
// reordered n=4u+g -> DPP 4x4 transpose keeps c-state in-lane.
template<int D, int H, int WAVES, int TPW, bool IN_F32, bool OUT_F32, bool LAST>
__global__ __launch_bounds__(WAVES * 64)
void lstm_pl(const void* __restrict__ xin,
             const float* __restrict__ Wih, const float* __restrict__ Whh,
             const float* __restrict__ bih, const float* __restrict__ bhh,
             void* __restrict__ yout, float* __restrict__ hn)
{
    constexpr int K    = D + H;
    constexpr int KF   = (K + 31) / 32;
    constexpr int SSTR = KF * 32 + 8;   // u16 stride: 16B-aligned rows, bank-spread
    constexpr int NT   = WAVES * 64;
    constexpr int XW   = 16 * D / 2;    // staging dwords per step
    static_assert(XW <= NT, "one staging dword per thread");
    static_assert(TPW * WAVES * 16 == 4 * H, "tile cover");

    const int tid  = threadIdx.x;
    const int lane = tid & 63;
    const int wv   = tid >> 6;
    const int q    = lane >> 4;
    const int cc   = lane & 15;
    const int b0   = blockIdx.x * 16;

    __shared__ u16 smem[2 * 16 * SSTR];
    u16* xc0 = smem;
    u16* xc1 = smem + 16 * SSTR;

    // ---- B-fragments (weights, gate-interleaved cols), bias, c-state ----
    bf16x8 WB[TPW][KF];
    float  bias[TPW][4];
    float  cst[TPW];
#pragma unroll
    for (int tp = 0; tp < TPW; ++tp) {
        const int nglob = (wv * TPW + tp) * 16 + cc;
        const int u = nglob >> 2, g = nglob & 3;
        const int row = g * H + u;
#pragma unroll
        for (int kf = 0; kf < KF; ++kf) {
            bf16x8 w;
#pragma unroll
            for (int jj = 0; jj < 8; ++jj) {
                const int k = kf * 32 + q * 8 + jj;
                float v = 0.0f;
                if (k < D)      v = Wih[row * D + k];
                else if (k < K) v = Whh[row * H + (k - D)];
                w[jj] = (__bf16)v;
            }
            WB[tp][kf] = w;
        }
        const int uu = (wv * TPW + tp) * 4 + (cc >> 2);
#pragma unroll
        for (int g2 = 0; g2 < 4; ++g2)
            bias[tp][g2] = bih[g2 * H + uu] + bhh[g2 * H + uu];
        cst[tp] = 0.0f;
    }

    // ---- init LDS (zeros incl. K..KF*32 padding), stage x_0 ----
    for (int i = tid; i < 2 * 16 * SSTR; i += NT) smem[i] = 0;
    lbar();
    const int xr = (XW < NT) ? (tid / (D / 2)) : (tid / (D / 2));
    const int xp = tid % (D / 2);
    const bool stg = (tid < XW);
    // running input index (dword units): row (b0+xr), step t, dword xp
    int xoff = ((b0 + xr) * T_) * (D / 2) + xp;     // max 8.4M, fits int
    if (stg) {
        unsigned pk;
        if constexpr (IN_F32) {
            const float2 f = ((const float2*)xin)[xoff];
            pk = (unsigned)f2bf(f.x) | ((unsigned)f2bf(f.y) << 16);
        } else {
            pk = ((const unsigned*)xin)[xoff];
        }
        *(unsigned*)&xc0[xr * SSTR + 2 * xp] = pk;
    }
    xoff += D / 2;                                   // points at t=1
    lbar();

    const f32x4 zed = {0.0f, 0.0f, 0.0f, 0.0f};
    const int  rr = 4 * q + (lane & 3);              // batch row after transpose
    const int  u0 = wv * TPW * 4 + (cc >> 2);        // first unit this lane owns
    const bool bA = lane & 1, bB = lane & 2;
    // running output index: ((b0+rr)*T + t)*H + u0, advanced by H per step
    int ooff = ((b0 + rr) * T_) * H + u0;            // max 33.5M, fits int
    const int hbase = D + u0;                        // LDS h slot for tp=0

    for (int t = 0; t < T_; ++t) {
        u16* cur = (t & 1) ? xc1 : xc0;
        u16* nxt = (t & 1) ? xc0 : xc1;

        // ---- A-fragments for step t ----
        bf16x8 A[KF];
#pragma unroll
        for (int kf = 0; kf < KF; ++kf)
            A[kf] = *(const bf16x8*)&cur[cc * SSTR + kf * 32 + q * 8];

        // ---- prefetch x_{t+1} (vmcnt waited only at the ds_write below) ----
        unsigned pk = 0;
        const bool hasx = stg && (t + 1 < T_);
        if (hasx) {
            if constexpr (IN_F32) {
                const float2 f = ((const float2*)xin)[xoff];
                pk = (unsigned)f2bf(f.x) | ((unsigned)f2bf(f.y) << 16);
            } else {
                pk = ((const unsigned*)xin)[xoff];
            }
        }
        xoff += D / 2;

        // ---- MFMA: preact[16 x 4H] ----
        f32x4 acc[TPW];
#pragma unroll
        for (int tp = 0; tp < TPW; ++tp) acc[tp] = zed;
#pragma unroll
        for (int kf = 0; kf < KF; ++kf)
#pragma unroll
            for (int tp = 0; tp < TPW; ++tp)
                acc[tp] = __builtin_amdgcn_mfma_f32_16x16x32_bf16(A[kf], WB[tp][kf], acc[tp], 0, 0, 0);

        // ---- DPP 4x4 transpose + gates + state update ----
#pragma unroll
        for (int tp = 0; tp < TPW; ++tp) {
            float v0 = acc[tp][0], v1 = acc[tp][1], v2 = acc[tp][2], v3 = acc[tp][3];
            float s;
            s = dppq<0xB1>(bA ? v0 : v1); if (bA) v0 = s; else v1 = s;
            s = dppq<0xB1>(bA ? v2 : v3); if (bA) v2 = s; else v3 = s;
            s = dppq<0x4E>(bB ? v0 : v2); if (bB) v0 = s; else v2 = s;
            s = dppq<0x4E>(bB ? v1 : v3); if (bB) v1 = s; else v3 = s;

            const float gi = sigf(v0 + bias[tp][0]);
            const float gf = sigf(v1 + bias[tp][1]);
            const float gg = tanhfast(v2 + bias[tp][2]);
            const float go = sigf(v3 + bias[tp][3]);
            const float c  = gf * cst[tp] + gi * gg;
            cst[tp] = c;
            const float h  = go * tanhfast(c);

            nxt[rr * SSTR + hbase + tp * 4] = f2bf(h);     // feed step t+1
            if constexpr (OUT_F32) {
                ((float*)yout)[ooff + tp * 4] = h;
                if (LAST && t == T_ - 1) hn[(b0 + rr) * H + u0 + tp * 4] = h;
            } else {
                ((u16*)yout)[ooff + tp * 4] = f2bf(h);
            }
        }
        ooff += H;

        // ---- stage x_{t+1} ----
        if (hasx) *(unsigned*)&nxt[xr * SSTR + 2 * xp] = pk;

        lbar();
    }
}

extern "C" void kernel_launch(void* const* d_in, const int* in_sizes, int n_in,
                              void* d_out, int out_size, void* d_ws, size_t ws_size,
                              hipStream_t stream)
{
    (void)in_sizes; (void)n_in; (void)out_size; (void)ws_size;
    const float* z    = (const float*)d_in[0];
    const float* Wih1 = (const float*)d_in[1];
    const float* Whh1 = (const float*)d_in[2];
    const float* bih1 = (const float*)d_in[3];
    const float* bhh1 = (const float*)d_in[4];
    const float* Wih2 = (const float*)d_in[5];
    const float* Whh2 = (const float*)d_in[6];
    const float* bih2 = (const float*)d_in[7];
    const float* bhh2 = (const float*)d_in[8];
    const float* Wih3 = (const float*)d_in[9];
    const float* Whh3 = (const float*)d_in[10];
    const float* bih3 = (const float*)d_in[11];
    const float* bhh3 = (const float*)d_in[12];

    // ws: [h1 bf16 B*T*32 | h2 bf16 B*T*48]; kernel boundaries give coherence
    u16* h1 = (u16*)d_ws;
    u16* h2 = h1 + (size_t)B_ * T_ * 32;

    float* out = (float*)d_out;                  // [B,T,128]
    float* hn  = out + (size_t)B_ * T_ * 128;    // [1,B,128]

    // L1: D=64 H=32  (8 tiles)  8 waves x 1 tile, 512 thr
    hipLaunchKernelGGL((lstm_pl<64, 32, 8, 1, true, false, false>),
                       dim3(32), dim3(512), 0, stream,
                       (const void*)z, Wih1, Whh1, bih1, bhh1, (void*)h1, (float*)nullptr);
    // L2: D=32 H=48  (12 tiles) 6 waves x 2 tiles, 384 thr
    hipLaunchKernelGGL((lstm_pl<32, 48, 6, 2, false, false, false>),
                       dim3(32), dim3(384), 0, stream,
                       (const void*)h1, Wih2, Whh2, bih2, bhh2, (void*)h2, (float*)nullptr);
    // L3: D=48 H=128 (32 tiles) 8 waves x 4 tiles, 512 thr
    hipLaunchKernelGGL((lstm_pl<48, 128, 8, 4, false, true, true>),
                       dim3(32), dim3(512), 0, stream,
                       (const void*)h2, Wih3, Whh3, bih3, bhh3, (void*)out, hn);
}